// Round 5
// baseline (250.360 us; speedup 1.0000x reference)
//
#include <hip/hip_runtime.h>
#include <math.h>

// Problem constants (from reference setup_inputs)
#define BS 32
#define CH 3
#define HH 512
#define WW 512
#define HWSZ (HH * WW)          // 262144
#define MOMENTUM 0.8
#define EPSILON 1e-5

// ---------------- stats kernel ----------------
// S1[c] = sum_b x[b,c,0,0]
// S2[c] = sum_{b,h,w} x^2
// S3[c] = sum_{b,h,w} x[h,w] * x[(-h)%H, (-w)%W]
//
// Row-mirror symmetry: rowsum(h) == rowsum((H-h)%H), so
// S3 = rowsum(0) + rowsum(256) + 2*sum_{h=1}^{255} rowsum(h).
// Every global row is fetched exactly once across the grid:
// rows 0..255 as A-rows, 257..511 as mirror (B) rows, 256 by q=64 blocks.
// Staging uses global_load_lds width-16 (no VGPR round trip, fully
// pipelined), then one barrier, then all compute runs out of LDS.

constexpr int RPC = 4;        // A-rows per chunk
constexpr int CHUNKS = 65;    // q=0..63: A rows 0..255; q=64: row 256
constexpr int NROWS = 2 * RPC;

__device__ __forceinline__ void gload_lds16(const float* g, float* l) {
    __builtin_amdgcn_global_load_lds(
        (const __attribute__((address_space(1))) void*)g,
        (__attribute__((address_space(3))) void*)l, 16, 0, 0);
}

__global__ __launch_bounds__(256) void stats_kernel(
    const float* __restrict__ x, double* __restrict__ sums) {
    const int plane = blockIdx.x / CHUNKS;   // 0..95 = b*3+c
    const int q     = blockIdx.x % CHUNKS;
    const int c     = plane % CH;
    const float* __restrict__ base = x + (size_t)plane * HWSZ;
    const int tid  = threadIdx.x;
    const int lane = tid & 63;

    __shared__ float lds[NROWS * WW];        // 16 KiB: rows 0..3 = A, 4..7 = B

    // ---- stage 8 rows via async global->LDS, 16B per lane per issue ----
#pragma unroll
    for (int j = 0; j < 4; ++j) {
        int Lw = ((tid >> 6) << 6) + 256 * j;      // wave-uniform float4 slot
        Lw = __builtin_amdgcn_readfirstlane(Lw);
        const int Ll   = Lw + lane;                // this lane's slot
        const int r8   = Ll >> 7;                  // staged row 0..7
        const int col4 = Ll & 127;
        int g;                                     // global row
        if (q == 64) g = 256;
        else g = (r8 < RPC) ? (q * RPC + r8)
                            : ((HH - (q * RPC + (r8 - RPC))) & (HH - 1));
        gload_lds16(base + g * WW + col4 * 4, &lds[Lw * 4]);
    }
    asm volatile("s_waitcnt vmcnt(0)" ::: "memory");
    __syncthreads();

    // ---- s2 over this thread's own staged slots (conflict-free reads) ----
    float s2 = 0.f;
#pragma unroll
    for (int j = 0; j < 4; ++j) {
        const int Ll = tid + 256 * j;
        const int r8 = Ll >> 7;
        bool cnt;
        if (q == 64)       cnt = (r8 == 0);              // row 256 once
        else if (r8 < RPC) cnt = true;                   // A rows 0..255
        else               cnt = !(q == 0 && r8 == RPC); // B rows 257..511
        if (cnt) {
            const float4 v = *reinterpret_cast<const float4*>(&lds[Ll * 4]);
            s2 += v.x * v.x + v.y * v.y + v.z * v.z + v.w * v.w;
        }
    }

    // ---- s3: one wave per A-row, partner read reversed from LDS ----
    float s1 = 0.f, s3 = 0.f;
    {
        const int r = tid >> 6;                    // A-row slot 0..3
        const int h = (q == 64) ? 256 : q * RPC + r;
        const bool go = (q < 64) || (r == 0);
        if (go) {
            const float fac = (h == 0 || h == 256) ? 1.f : 2.f;
            const float* arow = &lds[r * WW];
            const float* brow = &lds[(r + RPC) * WW];
            float acc = 0.f;
#pragma unroll
            for (int k = 0; k < 2; ++k) {
                const int w = (lane + 64 * k) * 4;
                const float4 a  = *reinterpret_cast<const float4*>(arow + w);
                // partners of w..w+3 = (512-w)%512, 511-w, 510-w, 509-w
                const float4 q1 = *reinterpret_cast<const float4*>(brow + ((508 - w) & (WW - 1)));
                const float4 q2 = *reinterpret_cast<const float4*>(brow + ((512 - w) & (WW - 1)));
                acc += a.x * q2.x + a.y * q1.w + a.z * q1.z + a.w * q1.y;
            }
            s3 = fac * acc;
            if (h == 0 && lane == 0) s1 = arow[0];  // x[b,c,0,0]
        }
    }

    // ---- wave shuffle reduce, cross-wave via LDS, one atomic per block ----
#pragma unroll
    for (int off = 32; off > 0; off >>= 1) {
        s1 += __shfl_down(s1, off);
        s2 += __shfl_down(s2, off);
        s3 += __shfl_down(s3, off);
    }
    __shared__ float red[3][4];
    const int wv = tid >> 6;
    if (lane == 0) { red[0][wv] = s1; red[1][wv] = s2; red[2][wv] = s3; }
    __syncthreads();
    if (tid == 0) {
        double t1 = 0.0, t2 = 0.0, t3 = 0.0;
#pragma unroll
        for (int j = 0; j < 4; ++j) {
            t1 += (double)red[0][j];
            t2 += (double)red[1][j];
            t3 += (double)red[2][j];
        }
        atomicAdd(&sums[c * 3 + 0], t1);
        atomicAdd(&sums[c * 3 + 1], t2);
        atomicAdd(&sums[c * 3 + 2], t3);
    }
}

// ---------------- finalize: per-channel scale/shift ----------------
__global__ void finalize_kernel(const double* __restrict__ sums,
                                const float* __restrict__ gamma,
                                const float* __restrict__ beta,
                                const float* __restrict__ rmean,
                                const float* __restrict__ rvar,
                                float* __restrict__ ss) {
    const int c = threadIdx.x;
    if (c >= CH) return;
    const double S1 = sums[c * 3 + 0];
    const double S2 = sums[c * 3 + 1];
    const double S3 = sums[c * 3 + 2];
    const double N = (double)BS * (double)HWSZ;      // bs*H*W
    const double mean = S1 / N;
    const double ex2  = (S2 + S3) / (2.0 * N * (double)HWSZ);  // /(2*bs*H^2*W^2)
    const double var  = ex2 - mean * mean;
    const double rm = (double)rmean[c] * MOMENTUM + (1.0 - MOMENTUM) * mean;
    const double rv = (double)rvar[c]  * MOMENTUM + (1.0 - MOMENTUM) * var;
    const double inv_std = 1.0 / sqrt(rv + EPSILON);
    const float scale = (float)((double)gamma[c] * inv_std);
    const float shift = (float)((double)beta[c] - (double)scale * rm);
    ss[c * 2 + 0] = scale;
    ss[c * 2 + 1] = shift;
}

// ---------------- elementwise normalize ----------------
__global__ __launch_bounds__(256) void norm_kernel(
    const float* __restrict__ x, const float* __restrict__ ss,
    float* __restrict__ out) {
    float sc[CH], sh[CH];
#pragma unroll
    for (int c = 0; c < CH; ++c) { sc[c] = ss[c * 2]; sh[c] = ss[c * 2 + 1]; }
    const int n4 = BS * CH * HWSZ / 4;                // 6,291,456
    const int stride = gridDim.x * blockDim.x;
    for (int i4 = blockIdx.x * blockDim.x + threadIdx.x; i4 < n4; i4 += stride) {
        const int c = (i4 >> 16) % CH;                // 65536 f4 per plane
        const float4 v = reinterpret_cast<const float4*>(x)[i4];
        const float s = sc[c], t = sh[c];
        float4 o;
        o.x = fmaf(v.x, s, t);
        o.y = fmaf(v.y, s, t);
        o.z = fmaf(v.z, s, t);
        o.w = fmaf(v.w, s, t);
        reinterpret_cast<float4*>(out)[i4] = o;
    }
}

extern "C" void kernel_launch(void* const* d_in, const int* in_sizes, int n_in,
                              void* d_out, int out_size, void* d_ws, size_t ws_size,
                              hipStream_t stream) {
    const float* x     = (const float*)d_in[0];
    const float* gamma = (const float*)d_in[1];
    const float* beta  = (const float*)d_in[2];
    const float* rmean = (const float*)d_in[3];
    const float* rvar  = (const float*)d_in[4];
    float* out = (float*)d_out;

    double* sums = (double*)d_ws;                     // 9 doubles
    float*  ss   = (float*)((char*)d_ws + 128);       // 6 floats

    hipMemsetAsync(d_ws, 0, 160, stream);
    stats_kernel<<<BS * CH * CHUNKS, 256, 0, stream>>>(x, sums);
    finalize_kernel<<<1, 64, 0, stream>>>(sums, gamma, beta, rmean, rvar, ss);
    norm_kernel<<<2048, 256, 0, stream>>>(x, ss, out);
}

// Round 6
// 156.977 us; speedup vs baseline: 1.5949x; 1.5949x over previous
//
#include <hip/hip_runtime.h>
#include <math.h>

// Problem constants (from reference setup_inputs)
#define BS 32
#define CH 3
#define HH 512
#define WW 512
#define HWSZ (HH * WW)          // 262144
#define MOMENTUM 0.8
#define EPSILON 1e-5

// ---------------- stats kernel ----------------
// S1[c] = sum_b x[b,c,0,0]
// S2[c] = sum_{b,h,w} x^2
// S3[c] = sum_{b,h,w} x[h,w] * x[(-h)%H, (-w)%W]
//
// Direct (no symmetry factor): every element appears as "A" exactly once.
// Per float4 A at (h, w..w+3) the partners are elements
//   (512-w)%512, 511-w, 510-w, 509-w   of row brow=(512-h)%512.
// q1 = f4 at (508-w)&511 supplies partners of w+1..w+3 (.w,.z,.y).
// q2 = f4 at (512-w)&511 supplies partner of w (.x) — and q2(lane) ==
// q1(lane-1) because w increases by 4 per lane. So one aligned f4 load +
// one __shfl_up covers all partners; lane 0 patches its q2.x with a
// 1-element load. 2 vector loads per 16B, fully unrolled -> deep pipeline.

constexpr int BPP = 32;          // blocks per plane
constexpr int F4_PER_BLOCK = HWSZ / 4 / BPP;   // 2048
constexpr int ITERS = F4_PER_BLOCK / 256;      // 8

__global__ __launch_bounds__(256) void stats_kernel(
    const float* __restrict__ x, double* __restrict__ sums) {
    const int plane = blockIdx.x >> 5;       // /BPP: 0..95 = b*3+c
    const int blk   = blockIdx.x & (BPP - 1);
    const int c     = plane % CH;
    const float* __restrict__ base = x + (size_t)plane * HWSZ;
    const int tid  = threadIdx.x;
    const int lane = tid & 63;

    float s1 = 0.f, s2 = 0.f, s3 = 0.f;

#pragma unroll
    for (int k = 0; k < ITERS; ++k) {
        const int o4 = blk * F4_PER_BLOCK + tid + k * 256;
        const int o  = o4 * 4;
        const int h  = o >> 9;               // row
        const int w  = o & (WW - 1);         // col (multiple of 4)
        const int brow = (HH - h) & (HH - 1);
        const float* __restrict__ browp = base + brow * WW;

        const float4 a  = *reinterpret_cast<const float4*>(base + o);
        const float4 q1 = *reinterpret_cast<const float4*>(browp + ((508 - w) & (WW - 1)));
        float q2x = __shfl_up(q1.x, 1);
        if (lane == 0) q2x = browp[(512 - w) & (WW - 1)];

        s2 += a.x * a.x + a.y * a.y + a.z * a.z + a.w * a.w;
        s3 += a.x * q2x + a.y * q1.w + a.z * q1.z + a.w * q1.y;
        if (o == 0) s1 += a.x;               // x[b,c,0,0] (blk 0, tid 0, k 0)
    }

    // ---- wave shuffle reduce, cross-wave via LDS, one atomic per block ----
#pragma unroll
    for (int off = 32; off > 0; off >>= 1) {
        s1 += __shfl_down(s1, off);
        s2 += __shfl_down(s2, off);
        s3 += __shfl_down(s3, off);
    }
    __shared__ float red[3][4];
    const int wv = tid >> 6;
    if (lane == 0) { red[0][wv] = s1; red[1][wv] = s2; red[2][wv] = s3; }
    __syncthreads();
    if (tid == 0) {
        double t1 = 0.0, t2 = 0.0, t3 = 0.0;
#pragma unroll
        for (int j = 0; j < 4; ++j) {
            t1 += (double)red[0][j];
            t2 += (double)red[1][j];
            t3 += (double)red[2][j];
        }
        atomicAdd(&sums[c * 3 + 0], t1);
        atomicAdd(&sums[c * 3 + 1], t2);
        atomicAdd(&sums[c * 3 + 2], t3);
    }
}

// ---------------- finalize: per-channel scale/shift ----------------
__global__ void finalize_kernel(const double* __restrict__ sums,
                                const float* __restrict__ gamma,
                                const float* __restrict__ beta,
                                const float* __restrict__ rmean,
                                const float* __restrict__ rvar,
                                float* __restrict__ ss) {
    const int c = threadIdx.x;
    if (c >= CH) return;
    const double S1 = sums[c * 3 + 0];
    const double S2 = sums[c * 3 + 1];
    const double S3 = sums[c * 3 + 2];
    const double N = (double)BS * (double)HWSZ;      // bs*H*W
    const double mean = S1 / N;
    const double ex2  = (S2 + S3) / (2.0 * N * (double)HWSZ);  // /(2*bs*H^2*W^2)
    const double var  = ex2 - mean * mean;
    const double rm = (double)rmean[c] * MOMENTUM + (1.0 - MOMENTUM) * mean;
    const double rv = (double)rvar[c]  * MOMENTUM + (1.0 - MOMENTUM) * var;
    const double inv_std = 1.0 / sqrt(rv + EPSILON);
    const float scale = (float)((double)gamma[c] * inv_std);
    const float shift = (float)((double)beta[c] - (double)scale * rm);
    ss[c * 2 + 0] = scale;
    ss[c * 2 + 1] = shift;
}

// ---------------- elementwise normalize ----------------
__global__ __launch_bounds__(256) void norm_kernel(
    const float* __restrict__ x, const float* __restrict__ ss,
    float* __restrict__ out) {
    float sc[CH], sh[CH];
#pragma unroll
    for (int c = 0; c < CH; ++c) { sc[c] = ss[c * 2]; sh[c] = ss[c * 2 + 1]; }
    const int n4 = BS * CH * HWSZ / 4;                // 6,291,456
    const int stride = gridDim.x * blockDim.x;
    for (int i4 = blockIdx.x * blockDim.x + threadIdx.x; i4 < n4; i4 += stride) {
        const int c = (i4 >> 16) % CH;                // 65536 f4 per plane
        const float4 v = reinterpret_cast<const float4*>(x)[i4];
        const float s = sc[c], t = sh[c];
        float4 o;
        o.x = fmaf(v.x, s, t);
        o.y = fmaf(v.y, s, t);
        o.z = fmaf(v.z, s, t);
        o.w = fmaf(v.w, s, t);
        reinterpret_cast<float4*>(out)[i4] = o;
    }
}

extern "C" void kernel_launch(void* const* d_in, const int* in_sizes, int n_in,
                              void* d_out, int out_size, void* d_ws, size_t ws_size,
                              hipStream_t stream) {
    const float* x     = (const float*)d_in[0];
    const float* gamma = (const float*)d_in[1];
    const float* beta  = (const float*)d_in[2];
    const float* rmean = (const float*)d_in[3];
    const float* rvar  = (const float*)d_in[4];
    float* out = (float*)d_out;

    double* sums = (double*)d_ws;                     // 9 doubles
    float*  ss   = (float*)((char*)d_ws + 128);       // 6 floats

    hipMemsetAsync(d_ws, 0, 160, stream);
    stats_kernel<<<BS * CH * BPP, 256, 0, stream>>>(x, sums);
    finalize_kernel<<<1, 64, 0, stream>>>(sums, gamma, beta, rmean, rvar, ss);
    norm_kernel<<<2048, 256, 0, stream>>>(x, ss, out);
}

// Round 7
// 149.664 us; speedup vs baseline: 1.6728x; 1.0489x over previous
//
#include <hip/hip_runtime.h>
#include <math.h>

// Problem constants (from reference setup_inputs)
#define BS 32
#define CH 3
#define HH 512
#define WW 512
#define HWSZ (HH * WW)          // 262144
#define MOMENTUM 0.8
#define EPSILON 1e-5

// ---------------- stats kernel ----------------
// S1[c] = sum_b x[b,c,0,0]
// S2[c] = sum_{b,h,w} x^2
// S3[c] = sum_{b,h,w} x[h,w] * x[(-h)%H, (-w)%W]
//
// Round-1-proven inner loop: per float4, one aligned vector load + 4
// independent scalar loads of the reversed partners (contiguous-reversed
// across the wave -> L1 absorbs; no shuffles, no divergence, nothing
// between a load and its FMA consumer except other independent loads).
// Only change vs round 1: grid 768 -> 3072 blocks (BPP 8 -> 32), which
// was the actual limiter (grid starvation, 3 blocks/CU).

constexpr int BPP = 32;                        // blocks per plane
constexpr int F4_PER_BLOCK = HWSZ / 4 / BPP;   // 2048
constexpr int ITERS = F4_PER_BLOCK / 256;      // 8

__global__ __launch_bounds__(256) void stats_kernel(
    const float* __restrict__ x, double* __restrict__ sums) {
    const int plane = blockIdx.x >> 5;         // /BPP: 0..95 = b*3+c
    const int blk   = blockIdx.x & (BPP - 1);
    const int c     = plane % CH;
    const float* __restrict__ base = x + (size_t)plane * HWSZ;
    const int tid = threadIdx.x;

    float s1 = 0.f, s2 = 0.f, s3 = 0.f;

#pragma unroll 4
    for (int k = 0; k < ITERS; ++k) {
        const int o4 = blk * F4_PER_BLOCK + tid + k * 256;
        const int o  = o4 * 4;
        const int h  = o >> 9;        // /512
        const int w  = o & (WW - 1);
        const float4 v = *reinterpret_cast<const float4*>(base + o);
        s2 += v.x * v.x + v.y * v.y + v.z * v.z + v.w * v.w;
        const int hr = (HH - h) & (HH - 1);
        const float* __restrict__ rrow = base + hr * WW;
        // partner cols for w+0..w+3 (contiguous reversed; wave covers the
        // full reversed 1KiB segment across r0..r3 so L1 absorbs the stride)
        const float r0 = rrow[(WW - w)     & (WW - 1)];
        const float r1 = rrow[(WW - w - 1) & (WW - 1)];
        const float r2 = rrow[(WW - w - 2) & (WW - 1)];
        const float r3 = rrow[(WW - w - 3) & (WW - 1)];
        s3 += v.x * r0 + v.y * r1 + v.z * r2 + v.w * r3;
        if (o == 0) s1 += v.x;        // x[b,c,0,0] (blk 0, tid 0, k 0)
    }

    // wave (64-lane) shuffle reduce, then cross-wave via LDS
#pragma unroll
    for (int off = 32; off > 0; off >>= 1) {
        s1 += __shfl_down(s1, off);
        s2 += __shfl_down(s2, off);
        s3 += __shfl_down(s3, off);
    }
    __shared__ float red[3][4];
    const int lane = tid & 63, wv = tid >> 6;
    if (lane == 0) { red[0][wv] = s1; red[1][wv] = s2; red[2][wv] = s3; }
    __syncthreads();
    if (tid == 0) {
        double t1 = 0.0, t2 = 0.0, t3 = 0.0;
#pragma unroll
        for (int j = 0; j < 4; ++j) {
            t1 += (double)red[0][j];
            t2 += (double)red[1][j];
            t3 += (double)red[2][j];
        }
        atomicAdd(&sums[c * 3 + 0], t1);
        atomicAdd(&sums[c * 3 + 1], t2);
        atomicAdd(&sums[c * 3 + 2], t3);
    }
}

// ---------------- finalize: per-channel scale/shift ----------------
__global__ void finalize_kernel(const double* __restrict__ sums,
                                const float* __restrict__ gamma,
                                const float* __restrict__ beta,
                                const float* __restrict__ rmean,
                                const float* __restrict__ rvar,
                                float* __restrict__ ss) {
    const int c = threadIdx.x;
    if (c >= CH) return;
    const double S1 = sums[c * 3 + 0];
    const double S2 = sums[c * 3 + 1];
    const double S3 = sums[c * 3 + 2];
    const double N = (double)BS * (double)HWSZ;      // bs*H*W
    const double mean = S1 / N;
    const double ex2  = (S2 + S3) / (2.0 * N * (double)HWSZ);  // /(2*bs*H^2*W^2)
    const double var  = ex2 - mean * mean;
    const double rm = (double)rmean[c] * MOMENTUM + (1.0 - MOMENTUM) * mean;
    const double rv = (double)rvar[c]  * MOMENTUM + (1.0 - MOMENTUM) * var;
    const double inv_std = 1.0 / sqrt(rv + EPSILON);
    const float scale = (float)((double)gamma[c] * inv_std);
    const float shift = (float)((double)beta[c] - (double)scale * rm);
    ss[c * 2 + 0] = scale;
    ss[c * 2 + 1] = shift;
}

// ---------------- elementwise normalize ----------------
__global__ __launch_bounds__(256) void norm_kernel(
    const float* __restrict__ x, const float* __restrict__ ss,
    float* __restrict__ out) {
    float sc[CH], sh[CH];
#pragma unroll
    for (int c = 0; c < CH; ++c) { sc[c] = ss[c * 2]; sh[c] = ss[c * 2 + 1]; }
    const int n4 = BS * CH * HWSZ / 4;                // 6,291,456
    const int stride = gridDim.x * blockDim.x;
    for (int i4 = blockIdx.x * blockDim.x + threadIdx.x; i4 < n4; i4 += stride) {
        const int c = (i4 >> 16) % CH;                // 65536 f4 per plane
        const float4 v = reinterpret_cast<const float4*>(x)[i4];
        const float s = sc[c], t = sh[c];
        float4 o;
        o.x = fmaf(v.x, s, t);
        o.y = fmaf(v.y, s, t);
        o.z = fmaf(v.z, s, t);
        o.w = fmaf(v.w, s, t);
        reinterpret_cast<float4*>(out)[i4] = o;
    }
}

extern "C" void kernel_launch(void* const* d_in, const int* in_sizes, int n_in,
                              void* d_out, int out_size, void* d_ws, size_t ws_size,
                              hipStream_t stream) {
    const float* x     = (const float*)d_in[0];
    const float* gamma = (const float*)d_in[1];
    const float* beta  = (const float*)d_in[2];
    const float* rmean = (const float*)d_in[3];
    const float* rvar  = (const float*)d_in[4];
    float* out = (float*)d_out;

    double* sums = (double*)d_ws;                     // 9 doubles
    float*  ss   = (float*)((char*)d_ws + 128);       // 6 floats

    hipMemsetAsync(d_ws, 0, 160, stream);
    stats_kernel<<<BS * CH * BPP, 256, 0, stream>>>(x, sums);
    finalize_kernel<<<1, 64, 0, stream>>>(sums, gamma, beta, rmean, rvar, ss);
    norm_kernel<<<2048, 256, 0, stream>>>(x, ss, out);
}

// Round 8
// 86.546 us; speedup vs baseline: 2.8928x; 1.7293x over previous
//
#include <hip/hip_runtime.h>
#include <math.h>

// Problem constants (from reference setup_inputs)
#define BS 32
#define CH 3
#define HH 512
#define WW 512
#define HWSZ (HH * WW)          // 262144
#define MOMENTUM 0.8
#define EPSILON 1e-5

// ---------------- stats kernel ----------------
// S1[c] = sum_b x[b,c,0,0]
// S2[c] = sum_{b,h,w} x^2
// S3[c] = sum_{b,h,w} x[h,w] * x[(-h)%H, (-w)%W]
//
// Flattened within a plane (e = 512h + w), the reversal partner is:
//   w>=1, any h : partner(e) = 262656 - e   (mod 262144 folds h==0 case)
//   w==0       : partner(e) = 262144 - e    (mod 262144 folds e==0 case)
// So for an aligned float4 at o (elements o..o+3, o%4==0):
//   partners of o+1..o+3 = elements (262652-o)+3..+1
//     -> ALIGNED f4 at q1=(262144+508-o)&mask, components .w,.z,.y
//   partner of o -> .x of ALIGNED f4 at q2=(262144+(w0?0:512)-o)&mask
// (w0 = (o%512==0); all indices verified in [0,262143], so no OOB.)
// Inner loop: 3 aligned vector loads + FMAs. No scalar gathers (r1's
// limiter: ~64cy per 64-lane gather), no shuffles, no divergence.
// Grid stays at the empirically-best 768 blocks (r7 proved 3072 is 1.76x
// WORSE for this memory path).

constexpr int BPP = 8;                         // blocks per plane
constexpr int F4_PER_BLOCK = HWSZ / 4 / BPP;   // 8192
constexpr int STAT_THREADS = 256;
constexpr int F4_PER_THREAD = F4_PER_BLOCK / STAT_THREADS;  // 32

__global__ __launch_bounds__(STAT_THREADS) void stats_kernel(
    const float* __restrict__ x, double* __restrict__ sums) {
    const int plane = blockIdx.x / BPP;        // 0..95 = b*3+c
    const int blk   = blockIdx.x % BPP;
    const int c     = plane % CH;
    const float* __restrict__ base = x + (size_t)plane * HWSZ;
    const int tid = threadIdx.x;
    const int start4 = blk * F4_PER_BLOCK;

    float s1 = 0.f, s2 = 0.f, s3 = 0.f;

#pragma unroll 4
    for (int k = 0; k < F4_PER_THREAD; ++k) {
        const int o4 = start4 + tid + k * STAT_THREADS;
        const int o  = o4 * 4;
        const float4 a = *reinterpret_cast<const float4*>(base + o);
        s2 += a.x * a.x + a.y * a.y + a.z * a.z + a.w * a.w;

        const bool w0 = (o & (WW - 1)) == 0;
        const int q1 = (HWSZ + 508 - o) & (HWSZ - 1);                  // aligned
        const int q2 = (HWSZ + (w0 ? 0 : 512) - o) & (HWSZ - 1);      // aligned
        const float4 p1 = *reinterpret_cast<const float4*>(base + q1);
        const float4 p2 = *reinterpret_cast<const float4*>(base + q2);
        s3 += a.x * p2.x + a.y * p1.w + a.z * p1.z + a.w * p1.y;

        if (o == 0) s1 += a.x;   // x[b,c,0,0]
    }

    // wave (64-lane) shuffle reduce, then cross-wave via LDS
#pragma unroll
    for (int off = 32; off > 0; off >>= 1) {
        s1 += __shfl_down(s1, off);
        s2 += __shfl_down(s2, off);
        s3 += __shfl_down(s3, off);
    }
    __shared__ float red[3][4];
    const int lane = tid & 63, wv = tid >> 6;
    if (lane == 0) { red[0][wv] = s1; red[1][wv] = s2; red[2][wv] = s3; }
    __syncthreads();
    if (tid == 0) {
        double t1 = 0.0, t2 = 0.0, t3 = 0.0;
#pragma unroll
        for (int j = 0; j < 4; ++j) {
            t1 += (double)red[0][j];
            t2 += (double)red[1][j];
            t3 += (double)red[2][j];
        }
        atomicAdd(&sums[c * 3 + 0], t1);
        atomicAdd(&sums[c * 3 + 1], t2);
        atomicAdd(&sums[c * 3 + 2], t3);
    }
}

// ---------------- finalize: per-channel scale/shift ----------------
__global__ void finalize_kernel(const double* __restrict__ sums,
                                const float* __restrict__ gamma,
                                const float* __restrict__ beta,
                                const float* __restrict__ rmean,
                                const float* __restrict__ rvar,
                                float* __restrict__ ss) {
    const int c = threadIdx.x;
    if (c >= CH) return;
    const double S1 = sums[c * 3 + 0];
    const double S2 = sums[c * 3 + 1];
    const double S3 = sums[c * 3 + 2];
    const double N = (double)BS * (double)HWSZ;      // bs*H*W
    const double mean = S1 / N;
    const double ex2  = (S2 + S3) / (2.0 * N * (double)HWSZ);  // /(2*bs*H^2*W^2)
    const double var  = ex2 - mean * mean;
    const double rm = (double)rmean[c] * MOMENTUM + (1.0 - MOMENTUM) * mean;
    const double rv = (double)rvar[c]  * MOMENTUM + (1.0 - MOMENTUM) * var;
    const double inv_std = 1.0 / sqrt(rv + EPSILON);
    const float scale = (float)((double)gamma[c] * inv_std);
    const float shift = (float)((double)beta[c] - (double)scale * rm);
    ss[c * 2 + 0] = scale;
    ss[c * 2 + 1] = shift;
}

// ---------------- elementwise normalize ----------------
__global__ __launch_bounds__(256) void norm_kernel(
    const float* __restrict__ x, const float* __restrict__ ss,
    float* __restrict__ out) {
    float sc[CH], sh[CH];
#pragma unroll
    for (int c = 0; c < CH; ++c) { sc[c] = ss[c * 2]; sh[c] = ss[c * 2 + 1]; }
    const int n4 = BS * CH * HWSZ / 4;                // 6,291,456
    const int stride = gridDim.x * blockDim.x;
    for (int i4 = blockIdx.x * blockDim.x + threadIdx.x; i4 < n4; i4 += stride) {
        const int c = (i4 >> 16) % CH;                // 65536 f4 per plane
        const float4 v = reinterpret_cast<const float4*>(x)[i4];
        const float s = sc[c], t = sh[c];
        float4 o;
        o.x = fmaf(v.x, s, t);
        o.y = fmaf(v.y, s, t);
        o.z = fmaf(v.z, s, t);
        o.w = fmaf(v.w, s, t);
        reinterpret_cast<float4*>(out)[i4] = o;
    }
}

extern "C" void kernel_launch(void* const* d_in, const int* in_sizes, int n_in,
                              void* d_out, int out_size, void* d_ws, size_t ws_size,
                              hipStream_t stream) {
    const float* x     = (const float*)d_in[0];
    const float* gamma = (const float*)d_in[1];
    const float* beta  = (const float*)d_in[2];
    const float* rmean = (const float*)d_in[3];
    const float* rvar  = (const float*)d_in[4];
    float* out = (float*)d_out;

    double* sums = (double*)d_ws;                     // 9 doubles
    float*  ss   = (float*)((char*)d_ws + 128);       // 6 floats

    hipMemsetAsync(d_ws, 0, 160, stream);
    stats_kernel<<<BS * CH * BPP, STAT_THREADS, 0, stream>>>(x, sums);
    finalize_kernel<<<1, 64, 0, stream>>>(sums, gamma, beta, rmean, rvar, ss);
    norm_kernel<<<2048, 256, 0, stream>>>(x, ss, out);
}

// Round 9
// 67.630 us; speedup vs baseline: 3.7019x; 1.2797x over previous
//
#include <hip/hip_runtime.h>
#include <math.h>

// Problem constants (from reference setup_inputs)
#define BS 32
#define CH 3
#define HH 512
#define WW 512
#define HWSZ (HH * WW)          // 262144
#define MOMENTUM 0.8
#define EPSILON 1e-5

// ---------------- stats kernel ----------------
// S1[c] = sum_b x[b,c,0,0]
// S2[c] = sum_{b,h,w} x^2
// S3[c] = sum_{b,h,w} x[h,w] * x[(-h)%H, (-w)%W]
//
// Flattened within a plane (e = 512h + w):
//   w>=1 : partner(e) = (262656 - e) & 262143
//   w==0 : partner(e) = (262144 - e) & 262143
// For an aligned float4 at o: partners of o+1..o+3 are .w,.z,.y of the
// aligned f4 at q1=(262144+508-o)&mask; partner of o is .x of the aligned
// f4 at q2=(262144+(w0?0:512)-o)&mask.  (verified, r8 passed)
//
// r8 diagnosis: only ~1.6 wave-loads in flight per CU (VGPR=32 schedule,
// 3 blocks/CU). Fix: batch 4 triples (12 float4 loads) before consuming,
// and 6 blocks/CU. Per-block partials -> d_ws (no atomics, no memset).

constexpr int BPP = 16;                        // blocks per plane
constexpr int F4_PER_BLOCK = HWSZ / 4 / BPP;   // 4096
constexpr int STAT_THREADS = 256;
constexpr int F4_PER_THREAD = F4_PER_BLOCK / STAT_THREADS;  // 16
constexpr int BATCH = 4;
constexpr int NBATCH = F4_PER_THREAD / BATCH;  // 4
constexpr int NBLOCKS = BS * CH * BPP;         // 1536

__global__ __launch_bounds__(STAT_THREADS) void stats_kernel(
    const float* __restrict__ x, float4* __restrict__ partials) {
    const int plane = blockIdx.x / BPP;        // 0..95 = b*3+c
    const int blk   = blockIdx.x % BPP;
    const float* __restrict__ base = x + (size_t)plane * HWSZ;
    const int tid = threadIdx.x;
    const int start4 = blk * F4_PER_BLOCK;

    float s1 = 0.f, s2 = 0.f, s3 = 0.f;

    for (int nb = 0; nb < NBATCH; ++nb) {
        float4 a[BATCH], p1[BATCH], p2[BATCH];
#pragma unroll
        for (int j = 0; j < BATCH; ++j) {
            const int o = (start4 + tid + (nb * BATCH + j) * STAT_THREADS) * 4;
            const bool w0 = (o & (WW - 1)) == 0;
            const int q1 = (HWSZ + 508 - o) & (HWSZ - 1);             // aligned
            const int q2 = (HWSZ + (w0 ? 0 : 512) - o) & (HWSZ - 1);  // aligned
            a[j]  = *reinterpret_cast<const float4*>(base + o);
            p1[j] = *reinterpret_cast<const float4*>(base + q1);
            p2[j] = *reinterpret_cast<const float4*>(base + q2);
        }
#pragma unroll
        for (int j = 0; j < BATCH; ++j) {
            const float4 a_ = a[j], p1_ = p1[j], p2_ = p2[j];
            s2 += a_.x * a_.x + a_.y * a_.y + a_.z * a_.z + a_.w * a_.w;
            s3 += a_.x * p2_.x + a_.y * p1_.w + a_.z * p1_.z + a_.w * p1_.y;
            const int o = (start4 + tid + (nb * BATCH + j) * STAT_THREADS) * 4;
            if (o == 0) s1 += a_.x;            // x[b,c,0,0]
        }
    }

    // wave (64-lane) shuffle reduce, then cross-wave via LDS
#pragma unroll
    for (int off = 32; off > 0; off >>= 1) {
        s1 += __shfl_down(s1, off);
        s2 += __shfl_down(s2, off);
        s3 += __shfl_down(s3, off);
    }
    __shared__ float red[3][4];
    const int lane = tid & 63, wv = tid >> 6;
    if (lane == 0) { red[0][wv] = s1; red[1][wv] = s2; red[2][wv] = s3; }
    __syncthreads();
    if (tid == 0) {
        float4 p;
        p.x = red[0][0] + red[0][1] + red[0][2] + red[0][3];
        p.y = red[1][0] + red[1][1] + red[1][2] + red[1][3];
        p.z = red[2][0] + red[2][1] + red[2][2] + red[2][3];
        p.w = 0.f;
        partials[blockIdx.x] = p;
    }
}

// ---------------- finalize: reduce partials, per-channel scale/shift ----------------
// one block per channel c; partials for c live at blockIdx = (b*CH+c)*BPP+blk
__global__ __launch_bounds__(256) void finalize_kernel(
    const float4* __restrict__ partials,
    const float* __restrict__ gamma, const float* __restrict__ beta,
    const float* __restrict__ rmean, const float* __restrict__ rvar,
    float* __restrict__ ss) {
    const int c = blockIdx.x;
    const int tid = threadIdx.x;
    const int per_c = BS * BPP;                // 512 partials per channel
    double t1 = 0.0, t2 = 0.0, t3 = 0.0;
    for (int k = tid; k < per_c; k += 256) {
        const int b = k / BPP, blk = k % BPP;
        const float4 p = partials[(b * CH + c) * BPP + blk];
        t1 += (double)p.x; t2 += (double)p.y; t3 += (double)p.z;
    }
#pragma unroll
    for (int off = 32; off > 0; off >>= 1) {
        t1 += __shfl_down(t1, off);
        t2 += __shfl_down(t2, off);
        t3 += __shfl_down(t3, off);
    }
    __shared__ double red[3][4];
    const int lane = tid & 63, wv = tid >> 6;
    if (lane == 0) { red[0][wv] = t1; red[1][wv] = t2; red[2][wv] = t3; }
    __syncthreads();
    if (tid == 0) {
        const double S1 = red[0][0] + red[0][1] + red[0][2] + red[0][3];
        const double S2 = red[1][0] + red[1][1] + red[1][2] + red[1][3];
        const double S3 = red[2][0] + red[2][1] + red[2][2] + red[2][3];
        const double N = (double)BS * (double)HWSZ;
        const double mean = S1 / N;
        const double ex2  = (S2 + S3) / (2.0 * N * (double)HWSZ);
        const double var  = ex2 - mean * mean;
        const double rm = (double)rmean[c] * MOMENTUM + (1.0 - MOMENTUM) * mean;
        const double rv = (double)rvar[c]  * MOMENTUM + (1.0 - MOMENTUM) * var;
        const double inv_std = 1.0 / sqrt(rv + EPSILON);
        const float scale = (float)((double)gamma[c] * inv_std);
        const float shift = (float)((double)beta[c] - (double)scale * rm);
        ss[c * 2 + 0] = scale;
        ss[c * 2 + 1] = shift;
    }
}

// ---------------- elementwise normalize ----------------
__global__ __launch_bounds__(256) void norm_kernel(
    const float* __restrict__ x, const float* __restrict__ ss,
    float* __restrict__ out) {
    float sc[CH], sh[CH];
#pragma unroll
    for (int c = 0; c < CH; ++c) { sc[c] = ss[c * 2]; sh[c] = ss[c * 2 + 1]; }
    const int n4 = BS * CH * HWSZ / 4;                // 6,291,456
    const int stride = gridDim.x * blockDim.x;
    for (int i4 = blockIdx.x * blockDim.x + threadIdx.x; i4 < n4; i4 += stride) {
        const int c = (i4 >> 16) % CH;                // 65536 f4 per plane
        const float4 v = reinterpret_cast<const float4*>(x)[i4];
        const float s = sc[c], t = sh[c];
        float4 o;
        o.x = fmaf(v.x, s, t);
        o.y = fmaf(v.y, s, t);
        o.z = fmaf(v.z, s, t);
        o.w = fmaf(v.w, s, t);
        reinterpret_cast<float4*>(out)[i4] = o;
    }
}

extern "C" void kernel_launch(void* const* d_in, const int* in_sizes, int n_in,
                              void* d_out, int out_size, void* d_ws, size_t ws_size,
                              hipStream_t stream) {
    const float* x     = (const float*)d_in[0];
    const float* gamma = (const float*)d_in[1];
    const float* beta  = (const float*)d_in[2];
    const float* rmean = (const float*)d_in[3];
    const float* rvar  = (const float*)d_in[4];
    float* out = (float*)d_out;

    float4* partials = (float4*)d_ws;                    // 1536 * 16B = 24 KiB
    float*  ss = (float*)((char*)d_ws + NBLOCKS * 16);   // 6 floats

    stats_kernel<<<NBLOCKS, STAT_THREADS, 0, stream>>>(x, partials);
    finalize_kernel<<<CH, 256, 0, stream>>>(partials, gamma, beta, rmean, rvar, ss);
    norm_kernel<<<2048, 256, 0, stream>>>(x, ss, out);
}

// Round 10
// 59.915 us; speedup vs baseline: 4.1786x; 1.1288x over previous
//
#include <hip/hip_runtime.h>
#include <math.h>

// Problem constants (from reference setup_inputs)
#define BS 32
#define CH 3
#define HH 512
#define WW 512
#define HWSZ (HH * WW)          // 262144
#define MOMENTUM 0.8
#define EPSILON 1e-5

// ---------------- stats kernel (mirror-symmetry halved) ----------------
// S1[c] = sum_b x[b,c,0,0]
// S2[c] = sum_{b,h,w} x^2
// S3[c] = sum_{b,h,w} x[h,w] * x[(-h)%H, (-w)%W]
//
// Index math (verified r8/r9): for aligned f4 at o, partners of o+1..o+3
// are .w,.z,.y of aligned f4 at q1=(262144+508-o)&mask; partner of o is
// .x of aligned f4 at q2=(262144+(w0?0:512)-o)&mask, w0=(o%512==0).
//
// Symmetry: product pairs (e, p(e)) are equal for e and p(e). Process only
// A-rows 0..256; rows 1..255 get factor 2 (their partners are rows
// 257..511), rows 0 and 256 are self-paired (factor 1). As w sweeps A-row
// h in [1,255], q1 sweeps partner row 512-h exactly once -> partner-row
// s2 comes free as sum(q1^2) (skipped for h==0, where q1 is row 0 itself).
// Every element counted exactly once; logical loads halved vs r9.

constexpr int BPP = 16;                        // blocks per plane (A-half)
constexpr int ROWS_PER_BLK = 16;               // A-rows 0..255
constexpr int STAT_THREADS = 256;
constexpr int F4_PER_THREAD = ROWS_PER_BLK * (WW / 4) / STAT_THREADS;  // 8
constexpr int BATCH = 4;
constexpr int NBATCH = F4_PER_THREAD / BATCH;  // 2
constexpr int NBLOCKS = BS * CH * BPP;         // 1536

__global__ __launch_bounds__(STAT_THREADS) void stats_kernel(
    const float* __restrict__ x, float4* __restrict__ partials) {
    const int plane = blockIdx.x / BPP;        // 0..95 = b*3+c
    const int blk   = blockIdx.x % BPP;
    const float* __restrict__ base = x + (size_t)plane * HWSZ;
    const int tid = threadIdx.x;
    const int h0  = blk * ROWS_PER_BLK;

    float s1 = 0.f, s2 = 0.f, s3 = 0.f;

    for (int nb = 0; nb < NBATCH; ++nb) {
        float4 a[BATCH], p1[BATCH], p2[BATCH];
#pragma unroll
        for (int j = 0; j < BATCH; ++j) {
            const int idx  = tid + (nb * BATCH + j) * STAT_THREADS; // 0..2047
            const int r    = idx >> 7;            // row-in-band 0..15
            const int col4 = idx & 127;
            const int o    = ((h0 + r) << 9) + (col4 << 2);
            const bool w0  = (col4 == 0);
            const int q1 = (HWSZ + 508 - o) & (HWSZ - 1);             // aligned
            const int q2 = (HWSZ + (w0 ? 0 : 512) - o) & (HWSZ - 1);  // aligned
            a[j]  = *reinterpret_cast<const float4*>(base + o);
            p1[j] = *reinterpret_cast<const float4*>(base + q1);
            p2[j] = *reinterpret_cast<const float4*>(base + q2);
        }
#pragma unroll
        for (int j = 0; j < BATCH; ++j) {
            const int idx = tid + (nb * BATCH + j) * STAT_THREADS;
            const int h   = h0 + (idx >> 7);
            const float4 a_ = a[j], p1_ = p1[j], p2_ = p2[j];
            const float asq = a_.x * a_.x + a_.y * a_.y + a_.z * a_.z + a_.w * a_.w;
            const float qsq = p1_.x * p1_.x + p1_.y * p1_.y + p1_.z * p1_.z + p1_.w * p1_.w;
            const float prd = a_.x * p2_.x + a_.y * p1_.w + a_.z * p1_.z + a_.w * p1_.y;
            const float two = (h == 0) ? 0.f : 1.f;   // h==0: self-paired row
            s2 += asq + two * qsq;                    // q1 row counted unless h==0
            s3 += (h == 0 ? 1.f : 2.f) * prd;
            if (h == 0 && idx == 0) s1 += a_.x;       // x[b,c,0,0]
        }
    }

    // ---- row 256 (self-paired, factor 1, no q1^2) on blk 0 ----
    if (blk == 0 && tid < 128) {
        const int o  = 256 * WW + tid * 4;
        const bool w0 = (tid == 0);
        const int q1 = (HWSZ + 508 - o) & (HWSZ - 1);
        const int q2 = (HWSZ + (w0 ? 0 : 512) - o) & (HWSZ - 1);
        const float4 a_  = *reinterpret_cast<const float4*>(base + o);
        const float4 p1_ = *reinterpret_cast<const float4*>(base + q1);
        const float4 p2_ = *reinterpret_cast<const float4*>(base + q2);
        s2 += a_.x * a_.x + a_.y * a_.y + a_.z * a_.z + a_.w * a_.w;
        s3 += a_.x * p2_.x + a_.y * p1_.w + a_.z * p1_.z + a_.w * p1_.y;
    }

    // wave (64-lane) shuffle reduce, then cross-wave via LDS
#pragma unroll
    for (int off = 32; off > 0; off >>= 1) {
        s1 += __shfl_down(s1, off);
        s2 += __shfl_down(s2, off);
        s3 += __shfl_down(s3, off);
    }
    __shared__ float red[3][4];
    const int lane = tid & 63, wv = tid >> 6;
    if (lane == 0) { red[0][wv] = s1; red[1][wv] = s2; red[2][wv] = s3; }
    __syncthreads();
    if (tid == 0) {
        float4 p;
        p.x = red[0][0] + red[0][1] + red[0][2] + red[0][3];
        p.y = red[1][0] + red[1][1] + red[1][2] + red[1][3];
        p.z = red[2][0] + red[2][1] + red[2][2] + red[2][3];
        p.w = 0.f;
        partials[blockIdx.x] = p;
    }
}

// ---------------- finalize: reduce partials, per-channel scale/shift ----------------
// one block per channel c; partials for c live at blockIdx = (b*CH+c)*BPP+blk
__global__ __launch_bounds__(256) void finalize_kernel(
    const float4* __restrict__ partials,
    const float* __restrict__ gamma, const float* __restrict__ beta,
    const float* __restrict__ rmean, const float* __restrict__ rvar,
    float* __restrict__ ss) {
    const int c = blockIdx.x;
    const int tid = threadIdx.x;
    const int per_c = BS * BPP;                // 512 partials per channel
    double t1 = 0.0, t2 = 0.0, t3 = 0.0;
    for (int k = tid; k < per_c; k += 256) {
        const int b = k / BPP, blk = k % BPP;
        const float4 p = partials[(b * CH + c) * BPP + blk];
        t1 += (double)p.x; t2 += (double)p.y; t3 += (double)p.z;
    }
#pragma unroll
    for (int off = 32; off > 0; off >>= 1) {
        t1 += __shfl_down(t1, off);
        t2 += __shfl_down(t2, off);
        t3 += __shfl_down(t3, off);
    }
    __shared__ double red[3][4];
    const int lane = tid & 63, wv = tid >> 6;
    if (lane == 0) { red[0][wv] = t1; red[1][wv] = t2; red[2][wv] = t3; }
    __syncthreads();
    if (tid == 0) {
        const double S1 = red[0][0] + red[0][1] + red[0][2] + red[0][3];
        const double S2 = red[1][0] + red[1][1] + red[1][2] + red[1][3];
        const double S3 = red[2][0] + red[2][1] + red[2][2] + red[2][3];
        const double N = (double)BS * (double)HWSZ;
        const double mean = S1 / N;
        const double ex2  = (S2 + S3) / (2.0 * N * (double)HWSZ);
        const double var  = ex2 - mean * mean;
        const double rm = (double)rmean[c] * MOMENTUM + (1.0 - MOMENTUM) * mean;
        const double rv = (double)rvar[c]  * MOMENTUM + (1.0 - MOMENTUM) * var;
        const double inv_std = 1.0 / sqrt(rv + EPSILON);
        const float scale = (float)((double)gamma[c] * inv_std);
        const float shift = (float)((double)beta[c] - (double)scale * rm);
        ss[c * 2 + 0] = scale;
        ss[c * 2 + 1] = shift;
    }
}

// ---------------- elementwise normalize ----------------
__global__ __launch_bounds__(256) void norm_kernel(
    const float* __restrict__ x, const float* __restrict__ ss,
    float* __restrict__ out) {
    float sc[CH], sh[CH];
#pragma unroll
    for (int c = 0; c < CH; ++c) { sc[c] = ss[c * 2]; sh[c] = ss[c * 2 + 1]; }
    const int n4 = BS * CH * HWSZ / 4;                // 6,291,456
    const int stride = gridDim.x * blockDim.x;
    for (int i4 = blockIdx.x * blockDim.x + threadIdx.x; i4 < n4; i4 += stride) {
        const int c = (i4 >> 16) % CH;                // 65536 f4 per plane
        const float4 v = reinterpret_cast<const float4*>(x)[i4];
        const float s = sc[c], t = sh[c];
        float4 o;
        o.x = fmaf(v.x, s, t);
        o.y = fmaf(v.y, s, t);
        o.z = fmaf(v.z, s, t);
        o.w = fmaf(v.w, s, t);
        reinterpret_cast<float4*>(out)[i4] = o;
    }
}

extern "C" void kernel_launch(void* const* d_in, const int* in_sizes, int n_in,
                              void* d_out, int out_size, void* d_ws, size_t ws_size,
                              hipStream_t stream) {
    const float* x     = (const float*)d_in[0];
    const float* gamma = (const float*)d_in[1];
    const float* beta  = (const float*)d_in[2];
    const float* rmean = (const float*)d_in[3];
    const float* rvar  = (const float*)d_in[4];
    float* out = (float*)d_out;

    float4* partials = (float4*)d_ws;                    // 1536 * 16B = 24 KiB
    float*  ss = (float*)((char*)d_ws + NBLOCKS * 16);   // 6 floats

    stats_kernel<<<NBLOCKS, STAT_THREADS, 0, stream>>>(x, partials);
    finalize_kernel<<<CH, 256, 0, stream>>>(partials, gamma, beta, rmean, rvar, ss);
    norm_kernel<<<2048, 256, 0, stream>>>(x, ss, out);
}